// Round 13
// baseline (1955.108 us; speedup 1.0000x reference)
//
#include <hip/hip_runtime.h>

#define B_    64
#define T_    1024
#define H_    1024
#define HALF_ 512
#define NWG_SCAN 128
#define HBUF_HALF 131072   // shorts per double-buffer half: 2*64*1024

typedef short bf16x8 __attribute__((ext_vector_type(8)));
typedef short bf16x4 __attribute__((ext_vector_type(4)));
typedef _Float16 f16x8 __attribute__((ext_vector_type(8)));
typedef float f32x4  __attribute__((ext_vector_type(4)));
typedef unsigned int u32x4 __attribute__((ext_vector_type(4)));
typedef unsigned int u32x2 __attribute__((ext_vector_type(2)));

__device__ __forceinline__ short f2h(float f) {
    return (short)__builtin_bit_cast(unsigned short, (_Float16)f);
}

// Packed f32x4 -> bf16x4 via v_cvt_pk_bf16_f32 (RNE).
__device__ __forceinline__ bf16x4 pk4(f32x4 v) {
    unsigned w0, w1;
    asm("v_cvt_pk_bf16_f32 %0, %1, %2" : "=v"(w0) : "v"(v.x), "v"(v.y));
    asm("v_cvt_pk_bf16_f32 %0, %1, %2" : "=v"(w1) : "v"(v.z), "v"(v.w));
    u32x2 r; r[0] = w0; r[1] = w1;
    return __builtin_bit_cast(bf16x4, r);
}

__device__ __forceinline__ float tanh_fast(float x) {
    return 1.0f - 2.0f / (__expf(2.0f * x) + 1.0f);
}

// LDS-only barrier: no vmcnt drain.
#define BAR() do { \
    __builtin_amdgcn_sched_barrier(0); \
    asm volatile("s_waitcnt lgkmcnt(0)" ::: "memory"); \
    __builtin_amdgcn_sched_barrier(0); \
    __builtin_amdgcn_s_barrier(); \
    __builtin_amdgcn_sched_barrier(0); \
} while (0)

// ---------------- Phase 1: gi = bf16(x) @ bf16(W_ih)^T + (b_ih + b_hh) --------
__global__ __launch_bounds__(256) void gi_gemm(
        const float* __restrict__ X, const float* __restrict__ Wih,
        const float* __restrict__ bih, const float* __restrict__ bhh,
        float* __restrict__ out) {
    __shared__ short As[128][40];
    __shared__ short Bs[128][40];
    const int bid = blockIdx.x;
    const int tn = bid & 7;
    const int tm = bid >> 3;
    const int tid = threadIdx.x;
    const int l  = tid & 63;
    const int w  = tid >> 6;
    const int wr = w >> 1, wc = w & 1;
    const int lc = l & 15,  lr = l >> 4;

    const float* Ab = X   + (size_t)tm * 128 * 1024;
    const float* Bb = Wih + (size_t)tn * 128 * 1024;
    const int srow = tid >> 3;
    const int sc4  = (tid & 7) * 4;

    f32x4 acc[4][4];
#pragma unroll
    for (int m = 0; m < 4; m++)
#pragma unroll
        for (int n = 0; n < 4; n++) acc[m][n] = (f32x4){0.f, 0.f, 0.f, 0.f};

    f32x4 ra[4], rb[4];
#pragma unroll
    for (int c = 0; c < 4; c++) {
        ra[c] = *reinterpret_cast<const f32x4*>(Ab + (size_t)(srow + 32*c) * 1024 + sc4);
        rb[c] = *reinterpret_cast<const f32x4*>(Bb + (size_t)(srow + 32*c) * 1024 + sc4);
    }

    for (int k0 = 0; k0 < 1024; k0 += 32) {
        __syncthreads();
#pragma unroll
        for (int c = 0; c < 4; c++) {
            *reinterpret_cast<bf16x4*>(&As[srow + 32*c][sc4]) = pk4(ra[c]);
            *reinterpret_cast<bf16x4*>(&Bs[srow + 32*c][sc4]) = pk4(rb[c]);
        }
        __syncthreads();
        if (k0 + 32 < 1024) {
            const float* Ak = Ab + k0 + 32;
            const float* Bk = Bb + k0 + 32;
#pragma unroll
            for (int c = 0; c < 4; c++) {
                ra[c] = *reinterpret_cast<const f32x4*>(Ak + (size_t)(srow + 32*c) * 1024 + sc4);
                rb[c] = *reinterpret_cast<const f32x4*>(Bk + (size_t)(srow + 32*c) * 1024 + sc4);
            }
        }
        bf16x8 af[4], bfr[4];
#pragma unroll
        for (int m = 0; m < 4; m++)
            af[m] = *reinterpret_cast<bf16x8*>(&As[wr*64 + m*16 + lc][lr*8]);
#pragma unroll
        for (int n = 0; n < 4; n++)
            bfr[n] = *reinterpret_cast<bf16x8*>(&Bs[wc*64 + n*16 + lc][lr*8]);
#pragma unroll
        for (int m = 0; m < 4; m++)
#pragma unroll
            for (int n = 0; n < 4; n++)
                acc[m][n] = __builtin_amdgcn_mfma_f32_16x16x32_bf16(af[m], bfr[n], acc[m][n], 0, 0, 0);
    }

#pragma unroll
    for (int n = 0; n < 4; n++) {
        const int col = tn*128 + wc*64 + n*16 + lc;
        const float bs = bih[col] + bhh[col];
#pragma unroll
        for (int m = 0; m < 4; m++) {
            const int row0 = tm*128 + wr*64 + m*16 + lr*4;
#pragma unroll
            for (int j = 0; j < 4; j++)
                out[(size_t)(row0 + j) * 1024 + col] = acc[m][n][j] + bs;
        }
    }
}

// ---------------- Phase 2: batch-partitioned barrier-free scan ---------------
// R12 proven scan + SWAPPED-MFMA output layout: mfma(W_frag, h_frag) makes
// each thread hold h_next[batch=lc][4 consecutive cols col0=s*64+w*16+lr*4].
// The h store (fp16 + epoch LSBs) issues DIRECTLY from registers right after
// tanh -- no LDS transpose, no barrier before the store -> producer-store
// visibility (the per-step critical-path term V) starts ~0.2-0.3us earlier.
// gi becomes one dwordx4/thread; out[] store direct (16B). BAR2 kept after
// stores purely as the hB-reuse guard. Protocol/epoch wire format unchanged
// (epoch = step%3+1, 0 invalid; even col -> LSB=epoch bit0, odd col -> bit1;
// hbuf zeroed per launch).
__global__ __launch_bounds__(256, 1) void rnn_scan(
        const float* __restrict__ Whh, float* __restrict__ out,
        short* __restrict__ hbuf) {
    __shared__ short hB[16 * 1024];   // h stage [16 batch][1024 k], swizzled
    const int wg = blockIdx.x;
    const int p  = wg >> 6;           // parity
    const int g  = (wg >> 4) & 3;     // batch group (16 batches)
    const int s  = wg & 15;           // col slice (64 cols)
    const int tid = threadIdx.x;
    const int l  = tid & 63;
    const int w  = tid >> 6;
    const int lc = l & 15, lr = l >> 4;
    const int sb = tid >> 4;          // staging batch row 0..15
    const int sg = tid & 15;          // staging granule index

    // W_hh rows [s*64 + w*16 + lc], fp32 -> fp16, direct to 128 VGPRs
    bf16x8 breg[32];
    {
        const float* wrow = Whh + (size_t)(s*64 + w*16 + lc) * 1024;
#pragma unroll
        for (int kc = 0; kc < 32; kc++) {
            f32x4 v0 = *reinterpret_cast<const f32x4*>(wrow + kc*32 + lr*8);
            f32x4 v1 = *reinterpret_cast<const f32x4*>(wrow + kc*32 + lr*8 + 4);
            bf16x8 q = { f2h(v0.x), f2h(v0.y), f2h(v0.z), f2h(v0.w),
                         f2h(v1.x), f2h(v1.y), f2h(v1.z), f2h(v1.w) };
            breg[kc] = q;
        }
    }

    const unsigned hload_base = (unsigned)((p*64 + g*16 + sb) * 1024 + sg*8);
    const int batch = lc;                       // thread's output batch
    const int col0  = s*64 + w*16 + lr*4;       // thread's 4 output cols
    const unsigned hst_base = (unsigned)((p*64 + g*16 + batch) * 1024 + col0);

    int dly = 8;   // adaptive pre-issue delay, units of s_sleep(1) (~28 ns)

    for (int step = 0; step < HALF_; step++) {
        const int tt = (p == 0) ? (2*step) : (step == 0 ? T_-1 : 2*step - 1);
        const int epw = step % 3 + 1;
        const int epv = (step + 2) % 3 + 1;   // prev step's epw
        f32x4 acc = (f32x4){0.f, 0.f, 0.f, 0.f};
        f32x4 giv;
        const unsigned ob = (unsigned)(((g*16 + batch) * T_ + tt) * H_ + col0);

        if (step) {
            // adaptive delay: let producers' stores reach the IC first
            for (int i = 0; i < dly; i++)
                asm volatile("s_sleep 1" ::: "memory");
            // 8 x 16B loads of this group's h (contiguous 32 KB per WG)
            bf16x8 hl[8];
            const short* hc = hbuf + (size_t)((step+1) & 1) * HBUF_HALF + hload_base;
#pragma unroll
            for (int c = 0; c < 8; c++)
                asm volatile("global_load_dwordx4 %0, %1, off sc0 sc1"
                             : "=v"(hl[c]) : "v"(hc + c*128) : "memory");
            // gi: one contiguous dwordx4 per thread (overlaps with h flight)
            {
                const float* ga = out + ob;
                asm volatile("global_load_dwordx4 %0, %1, off"
                             : "=v"(giv) : "v"(ga) : "memory");
            }
            const unsigned pat = (unsigned)((epv & 1) | (((epv >> 1) & 1) << 16));
            unsigned pend = 0;
            asm volatile("s_waitcnt vmcnt(1)" ::: "memory");   // h done, gi flying
            __builtin_amdgcn_sched_barrier(0);
#pragma unroll
            for (int c = 0; c < 8; c++) {
                u32x4 d = __builtin_bit_cast(u32x4, hl[c]);
                unsigned m = ((d[0] & 0x00010001u) ^ pat) | ((d[1] & 0x00010001u) ^ pat)
                           | ((d[2] & 0x00010001u) ^ pat) | ((d[3] & 0x00010001u) ^ pat);
                if (!__all(m == 0)) pend |= 1u << c;
            }
            const int hadRetry = (pend != 0);   // wave-uniform (set via __all)
            while (pend) {   // retry stale slots until producer stores land
#pragma unroll
                for (int c = 0; c < 8; c++)
                    if (pend & (1u << c))
                        asm volatile("global_load_dwordx4 %0, %1, off sc0 sc1"
                                     : "=v"(hl[c]) : "v"(hc + c*128) : "memory");
                asm volatile("s_waitcnt vmcnt(0)" ::: "memory");
                __builtin_amdgcn_sched_barrier(0);
#pragma unroll
                for (int c = 0; c < 8; c++) {
                    if (pend & (1u << c)) {
                        u32x4 d = __builtin_bit_cast(u32x4, hl[c]);
                        unsigned m = ((d[0] & 0x00010001u) ^ pat) | ((d[1] & 0x00010001u) ^ pat)
                                   | ((d[2] & 0x00010001u) ^ pat) | ((d[3] & 0x00010001u) ^ pat);
                        if (__all(m == 0)) pend &= ~(1u << c);
                    }
                }
            }
            // AIMD update (per-wave)
            dly = hadRetry ? (dly > 44 ? 48 : dly + 4) : (dly ? dly - 1 : 0);
            // stage to LDS, swizzled: granule g8 -> g8 ^ (row & 15)
#pragma unroll
            for (int c = 0; c < 8; c++) {
                bf16x4 lo = { hl[c][0], hl[c][1], hl[c][2], hl[c][3] };
                bf16x4 hi = { hl[c][4], hl[c][5], hl[c][6], hl[c][7] };
                const int g8 = (sg + c*16) * 2;
                *reinterpret_cast<bf16x4*>(&hB[sb*1024 + (((g8    ) ^ sb) << 2)]) = lo;
                *reinterpret_cast<bf16x4*>(&hB[sb*1024 + (((g8 + 1) ^ sb) << 2)]) = hi;
            }
            BAR();
            // fragment reads + SWAPPED MFMA: D[W-row][batch] so each thread
            // holds h_next[batch=lc][col0 .. col0+3]
            f32x4 a0 = (f32x4){0,0,0,0}, a1 = (f32x4){0,0,0,0};
            f32x4 a2 = (f32x4){0,0,0,0}, a3 = (f32x4){0,0,0,0};
#pragma unroll
            for (int kc = 0; kc < 32; kc += 4) {
#pragma unroll
                for (int q = 0; q < 4; q++) {
                    const int k8 = (kc + q) * 8 + lr * 2;
                    bf16x4 lo = *reinterpret_cast<const bf16x4*>(&hB[lc*1024 + (((k8    ) ^ lc) << 2)]);
                    bf16x4 hi = *reinterpret_cast<const bf16x4*>(&hB[lc*1024 + (((k8 + 1) ^ lc) << 2)]);
                    bf16x8 hf = { lo[0], lo[1], lo[2], lo[3], hi[0], hi[1], hi[2], hi[3] };
                    f32x4& aq = (q == 0) ? a0 : (q == 1) ? a1 : (q == 2) ? a2 : a3;
                    aq = __builtin_amdgcn_mfma_f32_16x16x32_f16(
                        __builtin_bit_cast(f16x8, breg[kc + q]),
                        __builtin_bit_cast(f16x8, hf), aq, 0, 0, 0);
                }
            }
            acc = (a0 + a1) + (a2 + a3);
        } else {
            const float* ga = out + ob;
            asm volatile("global_load_dwordx4 %0, %1, off"
                         : "=v"(giv) : "v"(ga) : "memory");
        }

        // gi ready (long since arrived during MFMA on steady-state steps)
        asm volatile("s_waitcnt vmcnt(0)" ::: "memory");
        __builtin_amdgcn_sched_barrier(0);

        // h = tanh(acc + gi); pack fp16 + epoch LSBs; store DIRECT from regs
        float hv0 = tanh_fast(acc[0] + giv[0]);
        float hv1 = tanh_fast(acc[1] + giv[1]);
        float hv2 = tanh_fast(acc[2] + giv[2]);
        float hv3 = tanh_fast(acc[3] + giv[3]);
        const unsigned e0 = (unsigned)(epw & 1);          // even col -> LSB bit
        const unsigned e1 = (unsigned)((epw >> 1) & 1);   // odd col  -> LSB bit
        unsigned u0 = ((unsigned)__builtin_bit_cast(unsigned short, (_Float16)hv0) & 0xFFFEu) | e0;
        unsigned u1 = ((unsigned)__builtin_bit_cast(unsigned short, (_Float16)hv1) & 0xFFFEu) | e1;
        unsigned u2 = ((unsigned)__builtin_bit_cast(unsigned short, (_Float16)hv2) & 0xFFFEu) | e0;
        unsigned u3 = ((unsigned)__builtin_bit_cast(unsigned short, (_Float16)hv3) & 0xFFFEu) | e1;
        u32x2 pk; pk[0] = u0 | (u1 << 16); pk[1] = u2 | (u3 << 16);

        if (step < HALF_ - 1) {   // h store: earliest possible issue, no LDS/BAR
            short* hn = hbuf + (size_t)(step & 1) * HBUF_HALF + hst_base;
            asm volatile("global_store_dwordx2 %0, %1, off sc0 sc1"
                         :: "v"(hn), "v"(pk) : "memory");
        }

        // out[] store direct from regs (16B/thread)
        {
            f32x4 ov; ov[0] = hv0; ov[1] = hv1; ov[2] = hv2; ov[3] = hv3;
            float* op_ = out + ob;
            asm volatile("global_store_dwordx4 %0, %1, off"
                         :: "v"(op_), "v"(ov) : "memory");
            if (p == 0 && step == HALF_ - 1) {
                float* fp_ = out + (size_t)B_*T_*H_ + (size_t)((g*16 + batch) * H_ + col0);
                asm volatile("global_store_dwordx4 %0, %1, off"
                             :: "v"(fp_), "v"(ov) : "memory");
            }
        }

        BAR();   // hB-reuse guard: all waves' MFMA reads done before next stage
    }
}

extern "C" void kernel_launch(void* const* d_in, const int* in_sizes, int n_in,
                              void* d_out, int out_size, void* d_ws, size_t ws_size,
                              hipStream_t stream) {
    const float* X   = (const float*)d_in[0];
    const float* Wih = (const float*)d_in[1];
    const float* Whh = (const float*)d_in[2];
    const float* bih = (const float*)d_in[3];
    const float* bhh = (const float*)d_in[4];
    float* out = (float*)d_out;

    short* hbuf = (short*)d_ws;   // [2 dbuf][2 p][64 b][1024] fp16 = 512 KB

    // Epoch 0 is invalid: zeroing hbuf rejects cross-graph-replay leftovers.
    hipMemsetAsync(hbuf, 0, (size_t)2 * HBUF_HALF * 2, stream);
    gi_gemm<<<dim3(4096), dim3(256), 0, stream>>>(X, Wih, bih, bhh, out);
    rnn_scan<<<dim3(NWG_SCAN), dim3(256), 0, stream>>>(Whh, out, hbuf);
}

// Round 14
// 1780.087 us; speedup vs baseline: 1.0983x; 1.0983x over previous
//
#include <hip/hip_runtime.h>

#define B_    64
#define T_    1024
#define H_    1024
#define HALF_ 512
#define NWG_SCAN 128
#define HBUF_HALF 131072   // shorts per double-buffer half: 2*64*1024

typedef short bf16x8 __attribute__((ext_vector_type(8)));
typedef short bf16x4 __attribute__((ext_vector_type(4)));
typedef _Float16 f16x8 __attribute__((ext_vector_type(8)));
typedef float f32x4  __attribute__((ext_vector_type(4)));
typedef unsigned int u32x4 __attribute__((ext_vector_type(4)));
typedef unsigned int u32x2 __attribute__((ext_vector_type(2)));

__device__ __forceinline__ short f2h(float f) {
    return (short)__builtin_bit_cast(unsigned short, (_Float16)f);
}

// Packed f32x4 -> bf16x4 via v_cvt_pk_bf16_f32 (RNE).
__device__ __forceinline__ bf16x4 pk4(f32x4 v) {
    unsigned w0, w1;
    asm("v_cvt_pk_bf16_f32 %0, %1, %2" : "=v"(w0) : "v"(v.x), "v"(v.y));
    asm("v_cvt_pk_bf16_f32 %0, %1, %2" : "=v"(w1) : "v"(v.z), "v"(v.w));
    u32x2 r; r[0] = w0; r[1] = w1;
    return __builtin_bit_cast(bf16x4, r);
}

__device__ __forceinline__ float tanh_fast(float x) {
    return 1.0f - 2.0f / (__expf(2.0f * x) + 1.0f);
}

// LDS-only barrier: no vmcnt drain.
#define BAR() do { \
    __builtin_amdgcn_sched_barrier(0); \
    asm volatile("s_waitcnt lgkmcnt(0)" ::: "memory"); \
    __builtin_amdgcn_sched_barrier(0); \
    __builtin_amdgcn_s_barrier(); \
    __builtin_amdgcn_sched_barrier(0); \
} while (0)

// ---------------- Phase 1: gi = bf16(x) @ bf16(W_ih)^T + (b_ih + b_hh) --------
__global__ __launch_bounds__(256) void gi_gemm(
        const float* __restrict__ X, const float* __restrict__ Wih,
        const float* __restrict__ bih, const float* __restrict__ bhh,
        float* __restrict__ out) {
    __shared__ short As[128][40];
    __shared__ short Bs[128][40];
    const int bid = blockIdx.x;
    const int tn = bid & 7;
    const int tm = bid >> 3;
    const int tid = threadIdx.x;
    const int l  = tid & 63;
    const int w  = tid >> 6;
    const int wr = w >> 1, wc = w & 1;
    const int lc = l & 15,  lr = l >> 4;

    const float* Ab = X   + (size_t)tm * 128 * 1024;
    const float* Bb = Wih + (size_t)tn * 128 * 1024;
    const int srow = tid >> 3;
    const int sc4  = (tid & 7) * 4;

    f32x4 acc[4][4];
#pragma unroll
    for (int m = 0; m < 4; m++)
#pragma unroll
        for (int n = 0; n < 4; n++) acc[m][n] = (f32x4){0.f, 0.f, 0.f, 0.f};

    f32x4 ra[4], rb[4];
#pragma unroll
    for (int c = 0; c < 4; c++) {
        ra[c] = *reinterpret_cast<const f32x4*>(Ab + (size_t)(srow + 32*c) * 1024 + sc4);
        rb[c] = *reinterpret_cast<const f32x4*>(Bb + (size_t)(srow + 32*c) * 1024 + sc4);
    }

    for (int k0 = 0; k0 < 1024; k0 += 32) {
        __syncthreads();
#pragma unroll
        for (int c = 0; c < 4; c++) {
            *reinterpret_cast<bf16x4*>(&As[srow + 32*c][sc4]) = pk4(ra[c]);
            *reinterpret_cast<bf16x4*>(&Bs[srow + 32*c][sc4]) = pk4(rb[c]);
        }
        __syncthreads();
        if (k0 + 32 < 1024) {
            const float* Ak = Ab + k0 + 32;
            const float* Bk = Bb + k0 + 32;
#pragma unroll
            for (int c = 0; c < 4; c++) {
                ra[c] = *reinterpret_cast<const f32x4*>(Ak + (size_t)(srow + 32*c) * 1024 + sc4);
                rb[c] = *reinterpret_cast<const f32x4*>(Bk + (size_t)(srow + 32*c) * 1024 + sc4);
            }
        }
        bf16x8 af[4], bfr[4];
#pragma unroll
        for (int m = 0; m < 4; m++)
            af[m] = *reinterpret_cast<bf16x8*>(&As[wr*64 + m*16 + lc][lr*8]);
#pragma unroll
        for (int n = 0; n < 4; n++)
            bfr[n] = *reinterpret_cast<bf16x8*>(&Bs[wc*64 + n*16 + lc][lr*8]);
#pragma unroll
        for (int m = 0; m < 4; m++)
#pragma unroll
            for (int n = 0; n < 4; n++)
                acc[m][n] = __builtin_amdgcn_mfma_f32_16x16x32_bf16(af[m], bfr[n], acc[m][n], 0, 0, 0);
    }

#pragma unroll
    for (int n = 0; n < 4; n++) {
        const int col = tn*128 + wc*64 + n*16 + lc;
        const float bs = bih[col] + bhh[col];
#pragma unroll
        for (int m = 0; m < 4; m++) {
            const int row0 = tm*128 + wr*64 + m*16 + lr*4;
#pragma unroll
            for (int j = 0; j < 4; j++)
                out[(size_t)(row0 + j) * 1024 + col] = acc[m][n][j] + bs;
        }
    }
}

// ---------------- Phase 2: batch-partitioned barrier-free scan ---------------
// Swapped-MFMA (mfma(W,h): thread holds h_next[batch=lc][col0..col0+3],
// verified R13) with COALESCING RESTORED everywhere (R13's regression):
//  - hbuf uses a producer-order layout: offset = s*1024 + w*256 + lr*64 + lc*4
//    shorts -> the direct post-tanh h store is 512B contiguous per wave.
//    Consumer decodes chunks (gidx = c*512 + tid*2; batch = gidx&15 (even) /
//    +1; g8 = gidx>>4) into the SAME hB[batch][col^batch] staging; fragment
//    reads and the epoch wire format (even col -> LSB=epoch bit0, odd ->
//    bit1, per dword) are bit-identical to the proven protocol.
//  - gi loaded coalesced per (sb,sg) and transposed via LDS giS (written
//    before BAR1, read after MFMA) -> no extra barrier.
//  - out[] stored coalesced via inverse-transpose htrF after BAR2.
// The h store issues DIRECTLY after tanh (no LDS transpose, no barrier) --
// producer-store visibility starts ~0.2-0.3us earlier. Epoch = step%3+1,
// 0 invalid; hbuf zeroed per launch; AIMD pre-issue delay kept (R12).
__global__ __launch_bounds__(256, 1) void rnn_scan(
        const float* __restrict__ Whh, float* __restrict__ out,
        short* __restrict__ hbuf) {
    __shared__ short hB[16 * 1024];   // h stage [16 batch][1024 k], swizzled
    __shared__ float giS[16 * 68];    // gi transpose [batch][col-in-slice+pad]
    __shared__ float htrF[16 * 68];   // out transpose [batch][col-in-slice+pad]
    const int wg = blockIdx.x;
    const int p  = wg >> 6;           // parity
    const int g  = (wg >> 4) & 3;     // batch group (16 batches)
    const int s  = wg & 15;           // col slice (64 cols)
    const int tid = threadIdx.x;
    const int l  = tid & 63;
    const int w  = tid >> 6;
    const int lc = l & 15, lr = l >> 4;
    const int sb = tid >> 4;          // coalesced-access batch row 0..15
    const int sg = tid & 15;          // coalesced-access granule index

    // W_hh rows [s*64 + w*16 + lc], fp32 -> fp16, direct to 128 VGPRs
    bf16x8 breg[32];
    {
        const float* wrow = Whh + (size_t)(s*64 + w*16 + lc) * 1024;
#pragma unroll
        for (int kc = 0; kc < 32; kc++) {
            f32x4 v0 = *reinterpret_cast<const f32x4*>(wrow + kc*32 + lr*8);
            f32x4 v1 = *reinterpret_cast<const f32x4*>(wrow + kc*32 + lr*8 + 4);
            bf16x8 q = { f2h(v0.x), f2h(v0.y), f2h(v0.z), f2h(v0.w),
                         f2h(v1.x), f2h(v1.y), f2h(v1.z), f2h(v1.w) };
            breg[kc] = q;
        }
    }

    const unsigned grp_base = (unsigned)((p*64 + g*16) * 1024);   // shorts
    // consumer chunk base: tid*8 shorts (+ c*2048); producer store offset:
    const unsigned hst_off = grp_base + (unsigned)(s*1024 + w*256 + lr*64 + lc*4);
    const int lcol = w*16 + lr*4;     // thread's col offset within the slice

    int dly = 8;   // adaptive pre-issue delay, units of s_sleep(1) (~28 ns)

    for (int step = 0; step < HALF_; step++) {
        const int tt = (p == 0) ? (2*step) : (step == 0 ? T_-1 : 2*step - 1);
        const int epw = step % 3 + 1;
        const int epv = (step + 2) % 3 + 1;   // prev step's epw
        f32x4 acc = (f32x4){0.f, 0.f, 0.f, 0.f};
        f32x4 giv;
        // coalesced gi address for this thread's (sb,sg) role
        const float* ga = out + (size_t)(((g*16 + sb) * T_ + tt) * H_ + s*64 + sg*4);

        if (step) {
            // adaptive delay: let producers' stores reach the IC first
            for (int i = 0; i < dly; i++)
                asm volatile("s_sleep 1" ::: "memory");
            // 8 x 16B loads of this group's h (contiguous 32 KB per WG)
            bf16x8 hl[8];
            const short* hc = hbuf + (size_t)((step+1) & 1) * HBUF_HALF
                            + grp_base + (unsigned)(tid*8);
#pragma unroll
            for (int c = 0; c < 8; c++)
                asm volatile("global_load_dwordx4 %0, %1, off sc0 sc1"
                             : "=v"(hl[c]) : "v"(hc + c*2048) : "memory");
            // gi: coalesced dwordx4 (overlaps with h flight)
            asm volatile("global_load_dwordx4 %0, %1, off"
                         : "=v"(giv) : "v"(ga) : "memory");
            const unsigned pat = (unsigned)((epv & 1) | (((epv >> 1) & 1) << 16));
            unsigned pend = 0;
            asm volatile("s_waitcnt vmcnt(1)" ::: "memory");   // h done, gi flying
            __builtin_amdgcn_sched_barrier(0);
#pragma unroll
            for (int c = 0; c < 8; c++) {
                u32x4 d = __builtin_bit_cast(u32x4, hl[c]);
                unsigned m = ((d[0] & 0x00010001u) ^ pat) | ((d[1] & 0x00010001u) ^ pat)
                           | ((d[2] & 0x00010001u) ^ pat) | ((d[3] & 0x00010001u) ^ pat);
                if (!__all(m == 0)) pend |= 1u << c;
            }
            const int hadRetry = (pend != 0);   // wave-uniform (set via __all)
            while (pend) {   // retry stale slots until producer stores land
#pragma unroll
                for (int c = 0; c < 8; c++)
                    if (pend & (1u << c))
                        asm volatile("global_load_dwordx4 %0, %1, off sc0 sc1"
                                     : "=v"(hl[c]) : "v"(hc + c*2048) : "memory");
                asm volatile("s_waitcnt vmcnt(0)" ::: "memory");
                __builtin_amdgcn_sched_barrier(0);
#pragma unroll
                for (int c = 0; c < 8; c++) {
                    if (pend & (1u << c)) {
                        u32x4 d = __builtin_bit_cast(u32x4, hl[c]);
                        unsigned m = ((d[0] & 0x00010001u) ^ pat) | ((d[1] & 0x00010001u) ^ pat)
                                   | ((d[2] & 0x00010001u) ^ pat) | ((d[3] & 0x00010001u) ^ pat);
                        if (__all(m == 0)) pend &= ~(1u << c);
                    }
                }
            }
            // AIMD update (per-wave)
            dly = hadRetry ? (dly > 44 ? 48 : dly + 4) : (dly ? dly - 1 : 0);
            // gi arrived long ago (had the full h round-trip); land into LDS
            asm volatile("s_waitcnt vmcnt(0)" ::: "memory");
            __builtin_amdgcn_sched_barrier(0);
            *reinterpret_cast<f32x4*>(&giS[sb*68 + sg*4]) = giv;
            // stage hB from the permuted layout: chunk c = granules
            // gidx0 = c*512 + tid*2 (batch gidx0&15, even) and gidx0+1
#pragma unroll
            for (int c = 0; c < 8; c++) {
                bf16x4 lo = { hl[c][0], hl[c][1], hl[c][2], hl[c][3] };
                bf16x4 hi = { hl[c][4], hl[c][5], hl[c][6], hl[c][7] };
                const int gidx0 = c*512 + tid*2;
                const int b0 = gidx0 & 15;
                const int g8 = gidx0 >> 4;
                *reinterpret_cast<bf16x4*>(&hB[b0*1024 + ((g8 ^ b0) << 2)]) = lo;
                *reinterpret_cast<bf16x4*>(&hB[(b0+1)*1024 + ((g8 ^ (b0+1)) << 2)]) = hi;
            }
            BAR();
            // fragment reads + SWAPPED MFMA: D[W-row][batch] -> each thread
            // holds h_next[batch=lc][col0 .. col0+3]
            f32x4 a0 = (f32x4){0,0,0,0}, a1 = (f32x4){0,0,0,0};
            f32x4 a2 = (f32x4){0,0,0,0}, a3 = (f32x4){0,0,0,0};
#pragma unroll
            for (int kc = 0; kc < 32; kc += 4) {
#pragma unroll
                for (int q = 0; q < 4; q++) {
                    const int k8 = (kc + q) * 8 + lr * 2;
                    bf16x4 lo = *reinterpret_cast<const bf16x4*>(&hB[lc*1024 + (((k8    ) ^ lc) << 2)]);
                    bf16x4 hi = *reinterpret_cast<const bf16x4*>(&hB[lc*1024 + (((k8 + 1) ^ lc) << 2)]);
                    bf16x8 hf = { lo[0], lo[1], lo[2], lo[3], hi[0], hi[1], hi[2], hi[3] };
                    f32x4& aq = (q == 0) ? a0 : (q == 1) ? a1 : (q == 2) ? a2 : a3;
                    aq = __builtin_amdgcn_mfma_f32_16x16x32_f16(
                        __builtin_bit_cast(f16x8, breg[kc + q]),
                        __builtin_bit_cast(f16x8, hf), aq, 0, 0, 0);
                }
            }
            acc = (a0 + a1) + (a2 + a3);
        } else {
            asm volatile("global_load_dwordx4 %0, %1, off"
                         : "=v"(giv) : "v"(ga) : "memory");
            asm volatile("s_waitcnt vmcnt(0)" ::: "memory");
            __builtin_amdgcn_sched_barrier(0);
            *reinterpret_cast<f32x4*>(&giS[sb*68 + sg*4]) = giv;
            BAR();
        }

        // read this thread's gi in the swapped layout [batch=lc][lcol..+3]
        f32x4 gi4 = *reinterpret_cast<f32x4*>(&giS[lc*68 + lcol]);

        // h = tanh(acc + gi); pack fp16 + epoch LSBs; DIRECT coalesced store
        float hv0 = tanh_fast(acc[0] + gi4[0]);
        float hv1 = tanh_fast(acc[1] + gi4[1]);
        float hv2 = tanh_fast(acc[2] + gi4[2]);
        float hv3 = tanh_fast(acc[3] + gi4[3]);
        const unsigned e0 = (unsigned)(epw & 1);          // even col -> LSB bit
        const unsigned e1 = (unsigned)((epw >> 1) & 1);   // odd col  -> LSB bit
        unsigned u0 = ((unsigned)__builtin_bit_cast(unsigned short, (_Float16)hv0) & 0xFFFEu) | e0;
        unsigned u1 = ((unsigned)__builtin_bit_cast(unsigned short, (_Float16)hv1) & 0xFFFEu) | e1;
        unsigned u2 = ((unsigned)__builtin_bit_cast(unsigned short, (_Float16)hv2) & 0xFFFEu) | e0;
        unsigned u3 = ((unsigned)__builtin_bit_cast(unsigned short, (_Float16)hv3) & 0xFFFEu) | e1;
        u32x2 pk; pk[0] = u0 | (u1 << 16); pk[1] = u2 | (u3 << 16);

        if (step < HALF_ - 1) {   // h store: earliest issue, 512B/wave contiguous
            short* hn = hbuf + (size_t)(step & 1) * HBUF_HALF + hst_off;
            asm volatile("global_store_dwordx2 %0, %1, off sc0 sc1"
                         :: "v"(hn), "v"(pk) : "memory");
        }

        // out[] via inverse transpose (off critical path, coalesced)
        {
            f32x4 hv; hv[0] = hv0; hv[1] = hv1; hv[2] = hv2; hv[3] = hv3;
            *reinterpret_cast<f32x4*>(&htrF[lc*68 + lcol]) = hv;
        }
        BAR();   // htrF ready AND hB/giS reads done before next stage
        {
            f32x4 ov = *reinterpret_cast<f32x4*>(&htrF[sb*68 + sg*4]);
            float* op_ = out + (size_t)(((g*16 + sb) * T_ + tt) * H_ + s*64 + sg*4);
            asm volatile("global_store_dwordx4 %0, %1, off"
                         :: "v"(op_), "v"(ov) : "memory");
            if (p == 0 && step == HALF_ - 1) {
                float* fp_ = out + (size_t)B_*T_*H_ + (size_t)((g*16 + sb) * H_ + s*64 + sg*4);
                asm volatile("global_store_dwordx4 %0, %1, off"
                             :: "v"(fp_), "v"(ov) : "memory");
            }
        }
    }
}

extern "C" void kernel_launch(void* const* d_in, const int* in_sizes, int n_in,
                              void* d_out, int out_size, void* d_ws, size_t ws_size,
                              hipStream_t stream) {
    const float* X   = (const float*)d_in[0];
    const float* Wih = (const float*)d_in[1];
    const float* Whh = (const float*)d_in[2];
    const float* bih = (const float*)d_in[3];
    const float* bhh = (const float*)d_in[4];
    float* out = (float*)d_out;

    short* hbuf = (short*)d_ws;   // [2 dbuf][2 p][64 b][1024] fp16 = 512 KB

    // Epoch 0 is invalid: zeroing hbuf rejects cross-graph-replay leftovers.
    hipMemsetAsync(hbuf, 0, (size_t)2 * HBUF_HALF * 2, stream);
    gi_gemm<<<dim3(4096), dim3(256), 0, stream>>>(X, Wih, bih, bhh, out);
    rnn_scan<<<dim3(NWG_SCAN), dim3(256), 0, stream>>>(Whh, out, hbuf);
}